// Round 3
// baseline (255.116 us; speedup 1.0000x reference)
//
#include <hip/hip_runtime.h>

#define BB 8
#define HH 1024
#define WW 1280
#define HW (HH * WW)

typedef float f2v __attribute__((ext_vector_type(2), aligned(4)));

__global__ __launch_bounds__(256) void synth_view_kernel(
    const float* __restrict__ img, const float* __restrict__ disp,
    const float* __restrict__ srcK, const float* __restrict__ tgtK,
    const float* __restrict__ trans, float* __restrict__ out)
{
    const int x0p = (blockIdx.x * 64 + threadIdx.x) * 4;   // 4 pixels per thread
    const int y   = blockIdx.y * 4 + threadIdx.y;
    const int b   = blockIdx.z;

    // ---- per-batch constant setup (wave-uniform inputs -> s_loads) ----
    const float* sK = srcK + b * 16;
    const float* tK = tgtK + b * 16;
    const float* tv = trans + b * 3;

    float a00 = sK[0], a01 = sK[1], a02 = sK[2];
    float a10 = sK[4], a11 = sK[5], a12 = sK[6];
    float a20 = sK[8], a21 = sK[9], a22 = sK[10];
    float det = a00*(a11*a22 - a12*a21)
              - a01*(a10*a22 - a12*a20)
              + a02*(a10*a21 - a11*a20);
    float rdet = 1.0f / det;
    float i00 =  (a11*a22 - a12*a21) * rdet;
    float i01 = -(a01*a22 - a02*a21) * rdet;
    float i02 =  (a01*a12 - a02*a11) * rdet;
    float i10 = -(a10*a22 - a12*a20) * rdet;
    float i11 =  (a00*a22 - a02*a20) * rdet;
    float i12 = -(a00*a12 - a02*a10) * rdet;
    float i20 =  (a10*a21 - a11*a20) * rdet;
    float i21 = -(a00*a21 - a01*a20) * rdet;
    float i22 =  (a00*a11 - a01*a10) * rdet;

    float t0 = tv[0], t1 = tv[1], t2 = tv[2];
    // P = (target_K4 @ T)[:3,:]
    // row0: [p00 p01 p02 | p03], row1: [p10 p11 p12 | p13], row2: [0 0 1 | t2]
    float p00 = tK[0],  p01 = tK[1],  p02 = tK[2];
    float p03 = tK[0]*t0 + tK[1]*t1 + tK[2]*t2 + tK[3];
    float p10 = tK[4],  p11 = tK[5],  p12 = tK[6];
    float p13 = tK[4]*t0 + tK[5]*t1 + tK[6]*t2 + tK[7];
    float p23 = t2;                       // cp_z = depth + t2  (round-2 bug: this was dropped)

    // M = P[:2,:3] @ invK  (projection of the unit-depth ray)
    float M0x = p00*i00 + p01*i10 + p02*i20;
    float M0y = p00*i01 + p01*i11 + p02*i21;
    float M0c = p00*i02 + p01*i12 + p02*i22;
    float M1x = p10*i00 + p11*i10 + p12*i20;
    float M1y = p10*i01 + p11*i11 + p12*i21;
    float M1c = p10*i02 + p11*i12 + p12*i22;

    // px = (M0.[x,y,1] + p03*sd) / (1 + p23*sd)   (num/den both divided by depth)
    // sx = px * W/(W-1) - 0.5
    const float min_disp = 1.0f / 255.0f;
    const float rng_disp = (1.0f / 10.0f) - (1.0f / 255.0f);
    const float kwx = (float)WW / (float)(WW - 1);
    const float kwy = (float)HH / (float)(HH - 1);

    float fy = (float)y, fx = (float)x0p;
    float nx = M0c + M0y * fy + M0x * fx;   // running numerator base for px
    float ny = M1c + M1y * fy + M1x * fx;   // running numerator base for py

    const int pixbase = b * HW + y * WW + x0p;
    const float4 d4 = *reinterpret_cast<const float4*>(disp + pixbase);
    const float dv[4] = {d4.x, d4.y, d4.z, d4.w};

    const float* imb = img + (size_t)b * 3 * HW;
    float acc0[4], acc1[4], acc2[4];

#pragma unroll
    for (int j = 0; j < 4; ++j) {
        float sd  = fmaf(rng_disp, dv[j], min_disp);       // scaled disparity = 1/depth
        float numx = fmaf(p03, sd, nx);
        float numy = fmaf(p13, sd, ny);
        float den  = fmaf(p23, sd, 1.0f);                  // cpz/depth
        float rz   = __builtin_amdgcn_rcpf(den);
        float sx = fmaf(numx * rz, kwx, -0.5f);
        float sy = fmaf(numy * rz, kwy, -0.5f);
        nx += M0x;
        ny += M1x;

        float fx0 = floorf(sx), fy0 = floorf(sy);
        float wx = sx - fx0, wy = sy - fy0;
        int ix = (int)fx0, iy = (int)fy0;
        int x0c = min(max(ix,     0), WW - 1);
        int x1c = min(max(ix + 1, 0), WW - 1);
        int y0c = min(max(iy,     0), HH - 1);
        int y1c = min(max(iy + 1, 0), HH - 1);
        int xl  = min(x0c, WW - 2);          // dwordx2 stays inside the row
        bool s0 = (x0c == xl);               // take .x for the x0 tap
        bool s1 = (x1c == xl + 1);           // take .y for the x1 tap

        int off0 = y0c * WW + xl;
        int off1 = y1c * WW + xl;

        float w11 = wx * wy;
        float w10 = wy - w11;                // (1-wx)*wy
        float w01 = wx - w11;                // wx*(1-wy)
        float w00 = 1.0f - wx - wy + w11;    // (1-wx)*(1-wy)

#pragma unroll
        for (int c = 0; c < 3; ++c) {
            const float* ic = imb + c * HW;
            f2v r0 = *reinterpret_cast<const f2v*>(ic + off0);
            f2v r1 = *reinterpret_cast<const f2v*>(ic + off1);
            float v00 = s0 ? r0.x : r0.y;
            float v01 = s1 ? r0.y : r0.x;
            float v10 = s0 ? r1.x : r1.y;
            float v11 = s1 ? r1.y : r1.x;
            float v = v00 * w00;
            v = fmaf(v01, w01, v);
            v = fmaf(v10, w10, v);
            v = fmaf(v11, w11, v);
            if (c == 0) acc0[j] = v;
            else if (c == 1) acc1[j] = v;
            else acc2[j] = v;
        }
    }

    float* ob = out + (size_t)b * 3 * HW + y * WW + x0p;
    *reinterpret_cast<float4*>(ob)            = make_float4(acc0[0], acc0[1], acc0[2], acc0[3]);
    *reinterpret_cast<float4*>(ob + HW)       = make_float4(acc1[0], acc1[1], acc1[2], acc1[3]);
    *reinterpret_cast<float4*>(ob + 2 * HW)   = make_float4(acc2[0], acc2[1], acc2[2], acc2[3]);
}

extern "C" void kernel_launch(void* const* d_in, const int* in_sizes, int n_in,
                              void* d_out, int out_size, void* d_ws, size_t ws_size,
                              hipStream_t stream) {
    const float* img   = (const float*)d_in[0];
    const float* disp  = (const float*)d_in[1];
    const float* srcK  = (const float*)d_in[2];
    const float* tgtK  = (const float*)d_in[3];
    const float* trans = (const float*)d_in[4];
    float* out = (float*)d_out;

    dim3 block(64, 4, 1);                 // 256 threads, 4 px each in x
    dim3 grid(WW / 256, HH / 4, BB);      // (5, 256, 8)
    synth_view_kernel<<<grid, block, 0, stream>>>(img, disp, srcK, tgtK, trans, out);
}

// Round 4
// 253.800 us; speedup vs baseline: 1.0052x; 1.0052x over previous
//
#include <hip/hip_runtime.h>

#define BB 8
#define HH 1024
#define WW 1280
#define HW (HH * WW)

// window: 6 rows x 264 cols per channel
#define WIN_W 264
#define WIN_ROWS 6
#define CH_PITCH (WIN_ROWS * WIN_W)   // 1584 floats
#define F4_PER_CH (CH_PITCH / 4)      // 396
#define F4_PER_ROW (WIN_W / 4)        // 66
#define N_F4 (3 * F4_PER_CH)          // 1188

typedef float f4u __attribute__((ext_vector_type(4), aligned(4)));
typedef float f4a __attribute__((ext_vector_type(4), aligned(16)));

__global__ __launch_bounds__(256) void synth_view_kernel(
    const float* __restrict__ img, const float* __restrict__ disp,
    const float* __restrict__ srcK, const float* __restrict__ tgtK,
    const float* __restrict__ trans, float* __restrict__ out)
{
    __shared__ __align__(16) float lds[3 * CH_PITCH];   // 19008 B

    const int bx = blockIdx.x * 256;          // tile x origin (256 px wide)
    const int by = blockIdx.y * 4;            // tile y origin (4 rows)
    const int b  = blockIdx.z;
    const int tx = threadIdx.x;               // 0..63
    const int ty = threadIdx.y;               // 0..3
    const int tid = ty * 64 + tx;

    // ---- per-batch constants (wave-uniform -> scalar pipe) ----
    const float* sK = srcK + b * 16;
    const float* tK = tgtK + b * 16;
    const float* tv = trans + b * 3;

    float a00 = sK[0], a01 = sK[1], a02 = sK[2];
    float a10 = sK[4], a11 = sK[5], a12 = sK[6];
    float a20 = sK[8], a21 = sK[9], a22 = sK[10];
    float det = a00*(a11*a22 - a12*a21)
              - a01*(a10*a22 - a12*a20)
              + a02*(a10*a21 - a11*a20);
    float rdet = 1.0f / det;
    float i00 =  (a11*a22 - a12*a21) * rdet;
    float i01 = -(a01*a22 - a02*a21) * rdet;
    float i02 =  (a01*a12 - a02*a11) * rdet;
    float i10 = -(a10*a22 - a12*a20) * rdet;
    float i11 =  (a00*a22 - a02*a20) * rdet;
    float i12 = -(a00*a12 - a02*a10) * rdet;
    float i20 =  (a10*a21 - a11*a20) * rdet;
    float i21 = -(a00*a21 - a01*a20) * rdet;
    float i22 =  (a00*a11 - a01*a10) * rdet;

    float t0 = tv[0], t1 = tv[1], t2 = tv[2];
    float p00 = tK[0],  p01 = tK[1],  p02 = tK[2];
    float p03 = tK[0]*t0 + tK[1]*t1 + tK[2]*t2 + tK[3];
    float p10 = tK[4],  p11 = tK[5],  p12 = tK[6];
    float p13 = tK[4]*t0 + tK[5]*t1 + tK[6]*t2 + tK[7];
    float p23 = t2;                                   // cp_z = depth + t2

    float M0x = p00*i00 + p01*i10 + p02*i20;
    float M0y = p00*i01 + p01*i11 + p02*i21;
    float M0c = p00*i02 + p01*i12 + p02*i22;
    float M1x = p10*i00 + p11*i10 + p12*i20;
    float M1y = p10*i01 + p11*i11 + p12*i21;
    float M1c = p10*i02 + p11*i12 + p12*i22;

    const float min_disp = 1.0f / 255.0f;
    const float rng_disp = (1.0f / 10.0f) - (1.0f / 255.0f);
    const float kwx = (float)WW / (float)(WW - 1);
    const float kwy = (float)HH / (float)(HH - 1);

    const int y = by + ty;

    // ---- prefetch disparity early (coalesced dwords, stride-64 px/thread) ----
    const float* db = disp + (size_t)b * HW + (size_t)y * WW + bx + tx;
    float dv[4];
#pragma unroll
    for (int j = 0; j < 4; ++j) dv[j] = db[64 * j];

    // ---- stage source window into LDS (coalesced float4, clamped content) ----
    const float* imb = img + (size_t)b * 3 * HW;
#pragma unroll
    for (int i = tid; i < N_F4; i += 256) {
        int ch  = i / F4_PER_CH;
        int rem = i - ch * F4_PER_CH;
        int row = rem / F4_PER_ROW;
        int c4  = rem - row * F4_PER_ROW;
        int gy  = min(max(by - 1 + row, 0), HH - 1);
        int gxb = bx - 1 + c4 * 4;
        const float* src = imb + (size_t)(ch * HH + gy) * WW;
        f4u v;
        if (gxb >= 0 && gxb + 3 < WW) {
            v = *reinterpret_cast<const f4u*>(src + gxb);
        } else {
            v.x = src[min(max(gxb,     0), WW - 1)];
            v.y = src[min(max(gxb + 1, 0), WW - 1)];
            v.z = src[min(max(gxb + 2, 0), WW - 1)];
            v.w = src[min(max(gxb + 3, 0), WW - 1)];
        }
        *reinterpret_cast<f4a*>(&lds[i * 4]) = v;
    }
    __syncthreads();

    // ---- gather + bilinear from LDS, 4 px/thread at stride 64 ----
    float fy = (float)y;
    float nx0 = M0c + M0y * fy + M0x * (float)(bx + tx);
    float ny0 = M1c + M1y * fy + M1x * (float)(bx + tx);
    float stepx = 64.0f * M0x;
    float stepy = 64.0f * M1x;

#pragma unroll
    for (int j = 0; j < 4; ++j) {
        int gx = bx + tx + 64 * j;
        float sd   = fmaf(rng_disp, dv[j], min_disp);   // scaled disp = 1/depth
        float numx = fmaf(p03, sd, nx0);
        float numy = fmaf(p13, sd, ny0);
        float den  = fmaf(p23, sd, 1.0f);               // cpz / depth
        float rz   = __builtin_amdgcn_rcpf(den);
        float sx = fmaf(numx * rz, kwx, -0.5f);
        float sy = fmaf(numy * rz, kwy, -0.5f);
        nx0 += stepx;
        ny0 += stepy;

        float fx0 = floorf(sx), fy0 = floorf(sy);
        float wx = sx - fx0, wy = sy - fy0;
        int lx = (int)fx0 - bx + 1;          // window col of x0 (content = clamp)
        int ly = (int)fy0 - by + 1;          // window row of y0
        lx = min(max(lx, 0), WIN_W - 2);     // proven in-bounds; clamp = OOB safety
        ly = min(max(ly, 0), WIN_ROWS - 2);

        float w11 = wx * wy;
        float w10 = wy - w11;
        float w01 = wx - w11;
        float w00 = 1.0f - wx - wy + w11;

        float* ob = out + (size_t)b * 3 * HW + (size_t)y * WW + gx;
        int base = ly * WIN_W + lx;
#pragma unroll
        for (int c = 0; c < 3; ++c) {
            const float* p0 = &lds[c * CH_PITCH + base];
            float v00 = p0[0],     v01 = p0[1];
            float v10 = p0[WIN_W], v11 = p0[WIN_W + 1];
            float v = v00 * w00;
            v = fmaf(v01, w01, v);
            v = fmaf(v10, w10, v);
            v = fmaf(v11, w11, v);
            ob[(size_t)c * HW] = v;
        }
    }
}

extern "C" void kernel_launch(void* const* d_in, const int* in_sizes, int n_in,
                              void* d_out, int out_size, void* d_ws, size_t ws_size,
                              hipStream_t stream) {
    const float* img   = (const float*)d_in[0];
    const float* disp  = (const float*)d_in[1];
    const float* srcK  = (const float*)d_in[2];
    const float* tgtK  = (const float*)d_in[3];
    const float* trans = (const float*)d_in[4];
    float* out = (float*)d_out;

    dim3 block(64, 4, 1);                 // 256 threads; 4 px/thread stride-64
    dim3 grid(WW / 256, HH / 4, BB);      // (5, 256, 8)
    synth_view_kernel<<<grid, block, 0, stream>>>(img, disp, srcK, tgtK, trans, out);
}